// Round 1
// baseline (1018.813 us; speedup 1.0000x reference)
//
#include <hip/hip_runtime.h>

#define BATCH 4
#define NPTS  131072
#define KSEL  128
#define FDIM  96
#define QDIM  128

#define G   64            // workgroups per batch
#define T   512           // threads per workgroup
#define P   (NPTS / (G * T))   // 4 points per thread
#define NW  (T / 64)      // waves per WG = 8

// ws layout (bytes):
//   0     : unsigned long long slots[BATCH][KSEL]   (FPS step winners)
//   4096  : unsigned long long fslots[BATCH][KSEL]  (feat argmax winners)
//   8192  : unsigned int arrive[BATCH*32]           (stride-32 for cacheline sep)
#define WS_SYNC_BYTES (4096 + 4096 + BATCH * 32 * 4)

__device__ __forceinline__ unsigned long long wave_max_u64(unsigned long long v) {
    #pragma unroll
    for (int off = 32; off > 0; off >>= 1) {
        unsigned long long o = __shfl_xor(v, off, 64);
        v = (v > o) ? v : o;
    }
    return v;
}

// d2 exactly as numpy: (dx*dx + dy*dy) + dz*dz, no FMA contraction
__device__ __forceinline__ float d2_np(float ax, float ay, float az,
                                       float bx, float by, float bz) {
    float dx = __fsub_rn(ax, bx);
    float dy = __fsub_rn(ay, by);
    float dz = __fsub_rn(az, bz);
    return __fadd_rn(__fadd_rn(__fmul_rn(dx, dx), __fmul_rn(dy, dy)),
                     __fmul_rn(dz, dz));
}

__global__ __launch_bounds__(T, 1) void fps_feat_kernel(
    const float* __restrict__ coords,          // [BATCH][NPTS][3]
    unsigned long long* __restrict__ slots,    // [BATCH][KSEL]
    unsigned long long* __restrict__ fslots,   // [BATCH][KSEL]
    unsigned int* __restrict__ arrive,         // [BATCH*32]
    float* __restrict__ out_sc)                // [BATCH][KSEL][3]
{
    const int wg  = blockIdx.x;
    const int b   = wg / G;
    const int wgb = wg % G;
    const int tid = threadIdx.x;
    const int wid = tid >> 6;
    const float* cb = coords + (size_t)b * NPTS * 3;

    const int base = wgb * T + tid;     // stride G*T = 32768 between my points

    float px[P], py[P], pz[P], md[P];
    #pragma unroll
    for (int j = 0; j < P; ++j) {
        int n = base + j * (G * T);
        px[j] = cb[n * 3 + 0];
        py[j] = cb[n * 3 + 1];
        pz[j] = cb[n * 3 + 2];
        md[j] = 1e10f;
    }

    __shared__ float s_samp[KSEL][3];
    __shared__ unsigned long long s_part[NW];
    __shared__ unsigned long long s_feat[KSEL][NW];
    __shared__ float s_cur[3];

    // first sampled point = index 0
    float cx = cb[0], cy = cb[1], cz = cb[2];
    if (tid == 0) {
        s_samp[0][0] = cx; s_samp[0][1] = cy; s_samp[0][2] = cz;
        if (wgb == 0) {
            out_sc[((size_t)b * KSEL + 0) * 3 + 0] = cx;
            out_sc[((size_t)b * KSEL + 0) * 3 + 1] = cy;
            out_sc[((size_t)b * KSEL + 0) * 3 + 2] = cz;
        }
    }
    __syncthreads();

    unsigned int* arr = &arrive[b * 32];

    for (int s = 1; s < KSEL; ++s) {
        // update min_d2 and local packed argmax (max d2, then min index)
        unsigned long long best = 0;
        #pragma unroll
        for (int j = 0; j < P; ++j) {
            float d2 = d2_np(px[j], py[j], pz[j], cx, cy, cz);
            float m = fminf(md[j], d2);
            md[j] = m;
            unsigned n = (unsigned)(base + j * (G * T));
            unsigned long long pk =
                ((unsigned long long)__float_as_uint(m) << 32) | (unsigned)(~n);
            best = (pk > best) ? pk : best;
        }
        unsigned long long wbest = wave_max_u64(best);
        if ((tid & 63) == 0) s_part[wid] = wbest;
        __syncthreads();

        if (tid == 0) {
            unsigned long long blk = s_part[0];
            #pragma unroll
            for (int w = 1; w < NW; ++w) {
                unsigned long long v = s_part[w];
                blk = (v > blk) ? v : blk;
            }
            atomicMax(&slots[b * KSEL + s], blk);
            __hip_atomic_fetch_add(arr, 1u, __ATOMIC_RELEASE,
                                   __HIP_MEMORY_SCOPE_AGENT);
            const unsigned target = (unsigned)(G * s);
            while (__hip_atomic_load(arr, __ATOMIC_ACQUIRE,
                                     __HIP_MEMORY_SCOPE_AGENT) < target) {
                __builtin_amdgcn_s_sleep(2);
            }
            unsigned long long win = __hip_atomic_load(
                &slots[b * KSEL + s], __ATOMIC_ACQUIRE, __HIP_MEMORY_SCOPE_AGENT);
            int widx = (int)(~(unsigned)(win & 0xFFFFFFFFull));
            float wx = cb[widx * 3 + 0];
            float wy = cb[widx * 3 + 1];
            float wz = cb[widx * 3 + 2];
            s_cur[0] = wx; s_cur[1] = wy; s_cur[2] = wz;
            s_samp[s][0] = wx; s_samp[s][1] = wy; s_samp[s][2] = wz;
            if (wgb == 0) {
                out_sc[((size_t)b * KSEL + s) * 3 + 0] = wx;
                out_sc[((size_t)b * KSEL + s) * 3 + 1] = wy;
                out_sc[((size_t)b * KSEL + s) * 3 + 2] = wz;
            }
        }
        __syncthreads();
        cx = s_cur[0]; cy = s_cur[1]; cz = s_cur[2];
    }

    // feat phase: for each sampled point k, argmax_n d2(coords[n], samp[k])
    for (int k = 0; k < KSEL; ++k) {
        float qx = s_samp[k][0], qy = s_samp[k][1], qz = s_samp[k][2];
        unsigned long long best = 0;
        #pragma unroll
        for (int j = 0; j < P; ++j) {
            float d2 = d2_np(px[j], py[j], pz[j], qx, qy, qz);
            unsigned n = (unsigned)(base + j * (G * T));
            unsigned long long pk =
                ((unsigned long long)__float_as_uint(d2) << 32) | (unsigned)(~n);
            best = (pk > best) ? pk : best;
        }
        unsigned long long wbest = wave_max_u64(best);
        if ((tid & 63) == 0) s_feat[k][wid] = wbest;
    }
    __syncthreads();
    if (tid < KSEL) {
        unsigned long long blk = s_feat[tid][0];
        #pragma unroll
        for (int w = 1; w < NW; ++w) {
            unsigned long long v = s_feat[tid][w];
            blk = (v > blk) ? v : blk;
        }
        atomicMax(&fslots[b * KSEL + tid], blk);
    }
    // kernel end = device-wide visibility for the stream-ordered MLP kernel
}

__global__ __launch_bounds__(QDIM, 1) void mlp_kernel(
    const float* __restrict__ features,   // [BATCH][NPTS][FDIM]
    const float* __restrict__ W1,         // [FDIM][QDIM]
    const float* __restrict__ b1,         // [QDIM]
    const float* __restrict__ W2,         // [QDIM][QDIM]
    const float* __restrict__ b2,         // [QDIM]
    const unsigned long long* __restrict__ fslots,  // [BATCH][KSEL]
    float* __restrict__ out_q)            // [BATCH][KSEL][QDIM]
{
    const int bk = blockIdx.x;            // b*KSEL + k
    const int b  = bk / KSEL;
    const int q  = threadIdx.x;

    __shared__ float fr[FDIM];
    __shared__ float h[QDIM];

    unsigned long long w = fslots[bk];
    int idx = (int)(~(unsigned)(w & 0xFFFFFFFFull));
    const float* frow = features + ((size_t)b * NPTS + idx) * FDIM;
    if (q < FDIM) fr[q] = frow[q];
    __syncthreads();

    float acc = b1[q];
    #pragma unroll 8
    for (int f = 0; f < FDIM; ++f) acc += fr[f] * W1[f * QDIM + q];
    h[q] = fmaxf(acc, 0.0f);
    __syncthreads();

    float acc2 = b2[q];
    #pragma unroll 8
    for (int j = 0; j < QDIM; ++j) acc2 += h[j] * W2[j * QDIM + q];
    out_q[(size_t)bk * QDIM + q] = acc2;
}

extern "C" void kernel_launch(void* const* d_in, const int* in_sizes, int n_in,
                              void* d_out, int out_size, void* d_ws, size_t ws_size,
                              hipStream_t stream) {
    (void)in_sizes; (void)n_in; (void)out_size; (void)ws_size;
    const float* coords   = (const float*)d_in[0];
    const float* features = (const float*)d_in[1];
    const float* W1       = (const float*)d_in[2];
    const float* b1       = (const float*)d_in[3];
    const float* W2       = (const float*)d_in[4];
    const float* b2       = (const float*)d_in[5];

    float* out_q  = (float*)d_out;
    float* out_sc = out_q + (size_t)BATCH * KSEL * QDIM;

    unsigned long long* slots  = (unsigned long long*)d_ws;
    unsigned long long* fslots = slots + BATCH * KSEL;
    unsigned int*       arrive = (unsigned int*)(fslots + BATCH * KSEL);

    hipMemsetAsync(d_ws, 0, WS_SYNC_BYTES, stream);
    fps_feat_kernel<<<BATCH * G, T, 0, stream>>>(coords, slots, fslots, arrive, out_sc);
    mlp_kernel<<<BATCH * KSEL, QDIM, 0, stream>>>(features, W1, b1, W2, b2, fslots, out_q);
}

// Round 2
// 865.104 us; speedup vs baseline: 1.1777x; 1.1777x over previous
//
#include <hip/hip_runtime.h>

#define BATCH 4
#define NPTS  131072
#define KSEL  128
#define FDIM  96
#define QDIM  128

#define G   8                    // workgroups per batch
#define T   1024                 // threads per workgroup
#define P   (NPTS / (G * T))     // 16 points per thread (in registers)
#define NW  (T / 64)             // 16 waves per WG

#define AG __HIP_MEMORY_SCOPE_AGENT

// 32B slot: one per (batch, step, wg). key==0 means "not yet written".
struct __align__(32) Slot {
    unsigned long long key;      // (d2_bits << 32) | ~index  -> max = (max d2, min idx)
    float x, y, z;
    unsigned int pad;
};

// ws: Slot slots[BATCH][KSEL][G]  (128 KiB)  then  u64 fslots[BATCH][KSEL] (4 KiB)
#define WS_SLOTS_BYTES   (BATCH * KSEL * G * (int)sizeof(Slot))
#define WS_TOTAL_BYTES   (WS_SLOTS_BYTES + BATCH * KSEL * 8)

// d2 exactly as numpy: (dx*dx + dy*dy) + dz*dz, no FMA contraction
__device__ __forceinline__ float d2_np(float ax, float ay, float az,
                                       float bx, float by, float bz) {
    float dx = __fsub_rn(ax, bx);
    float dy = __fsub_rn(ay, by);
    float dz = __fsub_rn(az, bz);
    return __fadd_rn(__fadd_rn(__fmul_rn(dx, dx), __fmul_rn(dy, dy)),
                     __fmul_rn(dz, dz));
}

__device__ __forceinline__ unsigned long long wave_max_u64(unsigned long long v) {
    #pragma unroll
    for (int off = 32; off > 0; off >>= 1) {
        unsigned long long o = __shfl_xor(v, off, 64);
        v = (v > o) ? v : o;
    }
    return v;
}

// reduce {key,x,y,z} by max key across the wave
__device__ __forceinline__ void wave_tuple_max(unsigned long long& k,
                                               float& x, float& y, float& z) {
    #pragma unroll
    for (int off = 32; off > 0; off >>= 1) {
        unsigned long long ok = __shfl_xor(k, off, 64);
        float ox = __shfl_xor(x, off, 64);
        float oy = __shfl_xor(y, off, 64);
        float oz = __shfl_xor(z, off, 64);
        if (ok > k) { k = ok; x = ox; y = oy; z = oz; }
    }
}

__global__ __launch_bounds__(T, 1) void fps_feat_kernel(
    const float* __restrict__ coords,          // [BATCH][NPTS][3]
    Slot* __restrict__ slots,                  // [BATCH][KSEL][G]
    unsigned long long* __restrict__ fslots,   // [BATCH][KSEL]
    float* __restrict__ out_sc)                // [BATCH][KSEL][3]
{
    const int b    = blockIdx.x / G;
    const int wgb  = blockIdx.x % G;
    const int tid  = threadIdx.x;
    const int wid  = tid >> 6;
    const int lane = tid & 63;
    const float* cb = coords + (size_t)b * NPTS * 3;

    const int base = wgb * T + tid;            // my first point; stride G*T

    float px[P], py[P], pz[P], md[P];
    #pragma unroll
    for (int j = 0; j < P; ++j) {
        int n = base + j * (G * T);
        px[j] = cb[n * 3 + 0];
        py[j] = cb[n * 3 + 1];
        pz[j] = cb[n * 3 + 2];
        md[j] = 1e10f;
    }

    __shared__ unsigned long long s_wk[NW];
    __shared__ float s_wx[NW], s_wy[NW], s_wz[NW];
    __shared__ float s_samp[KSEL][3];
    __shared__ float s_cur[3];
    __shared__ unsigned long long s_feat[KSEL][NW];

    // first sample = index 0
    float cx = cb[0], cy = cb[1], cz = cb[2];
    if (tid == 0) {
        s_samp[0][0] = cx; s_samp[0][1] = cy; s_samp[0][2] = cz;
        if (wgb == 0) {
            out_sc[((size_t)b * KSEL + 0) * 3 + 0] = cx;
            out_sc[((size_t)b * KSEL + 0) * 3 + 1] = cy;
            out_sc[((size_t)b * KSEL + 0) * 3 + 2] = cz;
        }
    }
    __syncthreads();

    for (int s = 1; s < KSEL; ++s) {
        // update min_d2, track local argmax tuple (key + coords, all in regs)
        unsigned long long best = 0;
        float bx = 0.f, by = 0.f, bz = 0.f;
        #pragma unroll
        for (int j = 0; j < P; ++j) {
            float d2 = d2_np(px[j], py[j], pz[j], cx, cy, cz);
            float m = fminf(md[j], d2);
            md[j] = m;
            unsigned n = (unsigned)(base + j * (G * T));
            unsigned long long pk =
                ((unsigned long long)__float_as_uint(m) << 32) | (unsigned)(~n);
            if (pk > best) { best = pk; bx = px[j]; by = py[j]; bz = pz[j]; }
        }
        wave_tuple_max(best, bx, by, bz);
        if (lane == 0) { s_wk[wid] = best; s_wx[wid] = bx; s_wy[wid] = by; s_wz[wid] = bz; }
        __syncthreads();

        if (tid == 0) {
            unsigned long long bk = s_wk[0];
            float wx = s_wx[0], wy = s_wy[0], wz = s_wz[0];
            #pragma unroll
            for (int w = 1; w < NW; ++w) {
                unsigned long long v = s_wk[w];
                if (v > bk) { bk = v; wx = s_wx[w]; wy = s_wy[w]; wz = s_wz[w]; }
            }
            Slot* sp = &slots[((size_t)b * KSEL + s) * G + wgb];
            __hip_atomic_store(&sp->x, wx, __ATOMIC_RELAXED, AG);
            __hip_atomic_store(&sp->y, wy, __ATOMIC_RELAXED, AG);
            __hip_atomic_store(&sp->z, wz, __ATOMIC_RELAXED, AG);
            __hip_atomic_store(&sp->key, bk, __ATOMIC_RELEASE, AG);
        }

        // wave 0: poll all G slots in parallel, tuple-reduce the winner
        if (wid == 0) {
            const Slot* srow = &slots[((size_t)b * KSEL + s) * G];
            unsigned long long k = 0;
            float sx = 0.f, sy = 0.f, sz = 0.f;
            if (lane < G) {
                const Slot* p = &srow[lane];
                do {
                    k = __hip_atomic_load(&p->key, __ATOMIC_ACQUIRE, AG);
                } while (k == 0);
                sx = __hip_atomic_load(&p->x, __ATOMIC_RELAXED, AG);
                sy = __hip_atomic_load(&p->y, __ATOMIC_RELAXED, AG);
                sz = __hip_atomic_load(&p->z, __ATOMIC_RELAXED, AG);
            }
            wave_tuple_max(k, sx, sy, sz);
            if (lane == 0) {
                s_cur[0] = sx; s_cur[1] = sy; s_cur[2] = sz;
                s_samp[s][0] = sx; s_samp[s][1] = sy; s_samp[s][2] = sz;
                if (wgb == 0) {
                    out_sc[((size_t)b * KSEL + s) * 3 + 0] = sx;
                    out_sc[((size_t)b * KSEL + s) * 3 + 1] = sy;
                    out_sc[((size_t)b * KSEL + s) * 3 + 2] = sz;
                }
            }
        }
        __syncthreads();
        cx = s_cur[0]; cy = s_cur[1]; cz = s_cur[2];
    }

    // feat phase: for each sampled point k, argmax_n d2 over all points
    for (int k = 0; k < KSEL; ++k) {
        float qx = s_samp[k][0], qy = s_samp[k][1], qz = s_samp[k][2];
        unsigned long long best = 0;
        #pragma unroll
        for (int j = 0; j < P; ++j) {
            float d2 = d2_np(px[j], py[j], pz[j], qx, qy, qz);
            unsigned n = (unsigned)(base + j * (G * T));
            unsigned long long pk =
                ((unsigned long long)__float_as_uint(d2) << 32) | (unsigned)(~n);
            if (pk > best) best = pk;
        }
        unsigned long long wbest = wave_max_u64(best);
        if (lane == 0) s_feat[k][wid] = wbest;
    }
    __syncthreads();
    if (tid < KSEL) {
        unsigned long long blk = s_feat[tid][0];
        #pragma unroll
        for (int w = 1; w < NW; ++w) {
            unsigned long long v = s_feat[tid][w];
            if (v > blk) blk = v;
        }
        atomicMax(&fslots[b * KSEL + tid], blk);
    }
}

__global__ __launch_bounds__(QDIM, 1) void mlp_kernel(
    const float* __restrict__ features,   // [BATCH][NPTS][FDIM]
    const float* __restrict__ W1,         // [FDIM][QDIM]
    const float* __restrict__ b1,         // [QDIM]
    const float* __restrict__ W2,         // [QDIM][QDIM]
    const float* __restrict__ b2,         // [QDIM]
    const unsigned long long* __restrict__ fslots,  // [BATCH][KSEL]
    float* __restrict__ out_q)            // [BATCH][KSEL][QDIM]
{
    const int bk = blockIdx.x;            // b*KSEL + k
    const int b  = bk / KSEL;
    const int q  = threadIdx.x;

    __shared__ float fr[FDIM];
    __shared__ float h[QDIM];

    unsigned long long w = fslots[bk];
    int idx = (int)(~(unsigned)(w & 0xFFFFFFFFull));
    const float* frow = features + ((size_t)b * NPTS + idx) * FDIM;
    if (q < FDIM) fr[q] = frow[q];
    __syncthreads();

    float acc = b1[q];
    #pragma unroll 8
    for (int f = 0; f < FDIM; ++f) acc += fr[f] * W1[f * QDIM + q];
    h[q] = fmaxf(acc, 0.0f);
    __syncthreads();

    float acc2 = b2[q];
    #pragma unroll 8
    for (int j = 0; j < QDIM; ++j) acc2 += h[j] * W2[j * QDIM + q];
    out_q[(size_t)bk * QDIM + q] = acc2;
}

extern "C" void kernel_launch(void* const* d_in, const int* in_sizes, int n_in,
                              void* d_out, int out_size, void* d_ws, size_t ws_size,
                              hipStream_t stream) {
    (void)in_sizes; (void)n_in; (void)out_size; (void)ws_size;
    const float* coords   = (const float*)d_in[0];
    const float* features = (const float*)d_in[1];
    const float* W1       = (const float*)d_in[2];
    const float* b1       = (const float*)d_in[3];
    const float* W2       = (const float*)d_in[4];
    const float* b2       = (const float*)d_in[5];

    float* out_q  = (float*)d_out;
    float* out_sc = out_q + (size_t)BATCH * KSEL * QDIM;

    Slot* slots = (Slot*)d_ws;
    unsigned long long* fslots =
        (unsigned long long*)((char*)d_ws + WS_SLOTS_BYTES);

    hipMemsetAsync(d_ws, 0, WS_TOTAL_BYTES, stream);
    fps_feat_kernel<<<BATCH * G, T, 0, stream>>>(coords, slots, fslots, out_sc);
    mlp_kernel<<<BATCH * KSEL, QDIM, 0, stream>>>(features, W1, b1, W2, b2, fslots, out_q);
}

// Round 3
// 410.279 us; speedup vs baseline: 2.4832x; 2.1086x over previous
//
#include <hip/hip_runtime.h>

#define BATCH 4
#define NPTS  131072
#define KSEL  128
#define FDIM  96
#define QDIM  128

#define G   32                   // workgroups per batch
#define T   512                  // threads per workgroup
#define P   (NPTS / (G * T))     // 8 points per thread (in registers)
#define NW  (T / 64)             // 8 waves per WG

#define AG __HIP_MEMORY_SCOPE_AGENT

// ws layout: u64 slots[BATCH][KSEL][G]   (FPS step partials, key==0 => unwritten)
//            u64 fparts[BATCH][KSEL][G]  (feat argmax partials)
#define WS_SLOTS_BYTES  (BATCH * KSEL * G * 8)
#define WS_TOTAL_BYTES  (2 * WS_SLOTS_BYTES)

// d2 exactly as numpy: (dx*dx + dy*dy) + dz*dz, no FMA contraction
__device__ __forceinline__ float d2_np(float ax, float ay, float az,
                                       float bx, float by, float bz) {
    float dx = __fsub_rn(ax, bx);
    float dy = __fsub_rn(ay, by);
    float dz = __fsub_rn(az, bz);
    return __fadd_rn(__fadd_rn(__fmul_rn(dx, dx), __fmul_rn(dy, dy)),
                     __fmul_rn(dz, dz));
}

__device__ __forceinline__ unsigned long long wave_max_u64(unsigned long long v) {
    #pragma unroll
    for (int off = 32; off > 0; off >>= 1) {
        unsigned long long o = __shfl_xor(v, off, 64);
        v = (v > o) ? v : o;
    }
    return v;
}

__global__ __launch_bounds__(T, 1) void fps_kernel(
    const float* __restrict__ coords,          // [BATCH][NPTS][3]
    unsigned long long* __restrict__ slots,    // [BATCH][KSEL][G]
    unsigned long long* __restrict__ fparts,   // [BATCH][KSEL][G]
    float* __restrict__ out_sc)                // [BATCH][KSEL][3]
{
    const int b    = blockIdx.x / G;
    const int wgb  = blockIdx.x % G;
    const int tid  = threadIdx.x;
    const int wid  = tid >> 6;
    const int lane = tid & 63;
    const float* cb = coords + (size_t)b * NPTS * 3;

    const int base = wgb * T + tid;            // my first point; stride G*T

    float px[P], py[P], pz[P], md[P];
    #pragma unroll
    for (int j = 0; j < P; ++j) {
        int n = base + j * (G * T);
        px[j] = cb[n * 3 + 0];
        py[j] = cb[n * 3 + 1];
        pz[j] = cb[n * 3 + 2];
        md[j] = 1e10f;
    }

    __shared__ unsigned long long s_md[NW];
    __shared__ unsigned long long s_ft[NW];
    __shared__ float s_cur[3];

    // first sample = index 0 (broadcast load, every thread)
    float cx = cb[0], cy = cb[1], cz = cb[2];
    if (tid == 0 && wgb == 0) {
        out_sc[((size_t)b * KSEL + 0) * 3 + 0] = cx;
        out_sc[((size_t)b * KSEL + 0) * 3 + 1] = cy;
        out_sc[((size_t)b * KSEL + 0) * 3 + 2] = cz;
    }

    for (int s = 1; s < KSEL; ++s) {
        // current sample = sample s-1. d2 to it serves BOTH the md update
        // (FPS) and the feat argmax for sample s-1 (folded feat phase).
        unsigned long long bmd = 0, bft = 0;
        #pragma unroll
        for (int j = 0; j < P; ++j) {
            float d2 = d2_np(px[j], py[j], pz[j], cx, cy, cz);
            unsigned inv = (unsigned)(~(unsigned)(base + j * (G * T)));
            unsigned long long pft =
                ((unsigned long long)__float_as_uint(d2) << 32) | inv;
            if (pft > bft) bft = pft;
            float m = fminf(md[j], d2);
            md[j] = m;
            unsigned long long pmd =
                ((unsigned long long)__float_as_uint(m) << 32) | inv;
            if (pmd > bmd) bmd = pmd;
        }
        #pragma unroll
        for (int off = 32; off > 0; off >>= 1) {
            unsigned long long o1 = __shfl_xor(bmd, off, 64);
            unsigned long long o2 = __shfl_xor(bft, off, 64);
            if (o1 > bmd) bmd = o1;
            if (o2 > bft) bft = o2;
        }
        if (lane == 0) { s_md[wid] = bmd; s_ft[wid] = bft; }
        __syncthreads();

        if (wid == 0) {
            unsigned long long kmd = 0, kft = 0;
            if (lane < NW) { kmd = s_md[lane]; kft = s_ft[lane]; }
            #pragma unroll
            for (int off = NW / 2; off > 0; off >>= 1) {
                unsigned long long o1 = __shfl_xor(kmd, off, 64);
                unsigned long long o2 = __shfl_xor(kft, off, 64);
                if (o1 > kmd) kmd = o1;
                if (o2 > kft) kft = o2;
            }
            if (lane == 0) {
                // self-contained relaxed stores: no fences / cache maintenance
                __hip_atomic_store(&slots[((size_t)b * KSEL + s) * G + wgb],
                                   kmd, __ATOMIC_RELAXED, AG);
                __hip_atomic_store(&fparts[((size_t)b * KSEL + (s - 1)) * G + wgb],
                                   kft, __ATOMIC_RELAXED, AG);
            }
            // poll all G partials for this step (relaxed; key!=0 => written)
            unsigned long long k = 0;
            if (lane < G) {
                const unsigned long long* p =
                    &slots[((size_t)b * KSEL + s) * G + lane];
                do {
                    k = __hip_atomic_load(p, __ATOMIC_RELAXED, AG);
                } while (k == 0);
            }
            k = wave_max_u64(k);
            if (lane == 0) {
                int idx = (int)(~(unsigned)(k & 0xFFFFFFFFull));
                float wx = cb[idx * 3 + 0];   // plain cacheable load (read-only)
                float wy = cb[idx * 3 + 1];
                float wz = cb[idx * 3 + 2];
                s_cur[0] = wx; s_cur[1] = wy; s_cur[2] = wz;
                if (wgb == 0) {
                    out_sc[((size_t)b * KSEL + s) * 3 + 0] = wx;
                    out_sc[((size_t)b * KSEL + s) * 3 + 1] = wy;
                    out_sc[((size_t)b * KSEL + s) * 3 + 2] = wz;
                }
            }
        }
        __syncthreads();
        cx = s_cur[0]; cy = s_cur[1]; cz = s_cur[2];
    }

    // post-loop: feat partial for sample 127 (cx.. currently = sample 127)
    {
        unsigned long long bft = 0;
        #pragma unroll
        for (int j = 0; j < P; ++j) {
            float d2 = d2_np(px[j], py[j], pz[j], cx, cy, cz);
            unsigned inv = (unsigned)(~(unsigned)(base + j * (G * T)));
            unsigned long long pft =
                ((unsigned long long)__float_as_uint(d2) << 32) | inv;
            if (pft > bft) bft = pft;
        }
        bft = wave_max_u64(bft);
        if (lane == 0) s_ft[wid] = bft;
        __syncthreads();
        if (wid == 0) {
            unsigned long long kft = 0;
            if (lane < NW) kft = s_ft[lane];
            #pragma unroll
            for (int off = NW / 2; off > 0; off >>= 1) {
                unsigned long long o = __shfl_xor(kft, off, 64);
                if (o > kft) kft = o;
            }
            if (lane == 0)
                __hip_atomic_store(&fparts[((size_t)b * KSEL + 127) * G + wgb],
                                   kft, __ATOMIC_RELAXED, AG);
        }
    }
}

__global__ __launch_bounds__(QDIM, 1) void mlp_kernel(
    const float* __restrict__ features,   // [BATCH][NPTS][FDIM]
    const float* __restrict__ W1,         // [FDIM][QDIM]
    const float* __restrict__ b1,         // [QDIM]
    const float* __restrict__ W2,         // [QDIM][QDIM]
    const float* __restrict__ b2,         // [QDIM]
    const unsigned long long* __restrict__ fparts,  // [BATCH][KSEL][G]
    float* __restrict__ out_q)            // [BATCH][KSEL][QDIM]
{
    const int bk = blockIdx.x;            // b*KSEL + k
    const int b  = bk / KSEL;
    const int q  = threadIdx.x;
    const int lane = q & 63;

    __shared__ float fr[FDIM];
    __shared__ float h[QDIM];
    __shared__ int s_idx;

    // merge the G feat partials for this (b,k)
    if (q < 64) {
        unsigned long long k = 0;
        if (lane < G) k = fparts[(size_t)bk * G + lane];
        k = wave_max_u64(k);
        if (lane == 0) s_idx = (int)(~(unsigned)(k & 0xFFFFFFFFull));
    }
    __syncthreads();

    const float* frow = features + ((size_t)b * NPTS + s_idx) * FDIM;
    if (q < FDIM) fr[q] = frow[q];
    __syncthreads();

    float acc = b1[q];
    #pragma unroll 8
    for (int f = 0; f < FDIM; ++f) acc += fr[f] * W1[f * QDIM + q];
    h[q] = fmaxf(acc, 0.0f);
    __syncthreads();

    float acc2 = b2[q];
    #pragma unroll 8
    for (int j = 0; j < QDIM; ++j) acc2 += h[j] * W2[j * QDIM + q];
    out_q[(size_t)bk * QDIM + q] = acc2;
}

extern "C" void kernel_launch(void* const* d_in, const int* in_sizes, int n_in,
                              void* d_out, int out_size, void* d_ws, size_t ws_size,
                              hipStream_t stream) {
    (void)in_sizes; (void)n_in; (void)out_size; (void)ws_size;
    const float* coords   = (const float*)d_in[0];
    const float* features = (const float*)d_in[1];
    const float* W1       = (const float*)d_in[2];
    const float* b1       = (const float*)d_in[3];
    const float* W2       = (const float*)d_in[4];
    const float* b2       = (const float*)d_in[5];

    float* out_q  = (float*)d_out;
    float* out_sc = out_q + (size_t)BATCH * KSEL * QDIM;

    unsigned long long* slots  = (unsigned long long*)d_ws;
    unsigned long long* fparts =
        (unsigned long long*)((char*)d_ws + WS_SLOTS_BYTES);

    hipMemsetAsync(d_ws, 0, WS_TOTAL_BYTES, stream);
    fps_kernel<<<BATCH * G, T, 0, stream>>>(coords, slots, fparts, out_sc);
    mlp_kernel<<<BATCH * KSEL, QDIM, 0, stream>>>(features, W1, b1, W2, b2,
                                                  fparts, out_q);
}